// Round 9
// baseline (542.916 us; speedup 1.0000x reference)
//
#include <hip/hip_runtime.h>
#include <hip/hip_bf16.h>
#include <hip/hip_fp16.h>

// Self-attention, N=8192 tokens, H=1024, fp32 in/out.
// fp16 MFMA GEMMs (mfma_f32_16x16x32_f16, fp32 acc), BT form.
//   1. x -> fp16; Wq/Wk/Wv -> fp16 transposed
//   2. q,k,v = x@W + b      (one batched dispatch, blockIdx.z = which)
//   3. S = q@k^T  fp16      (128 MB ws)
//   4. softmax + in-place compaction -> (idx<<16|half) pairs, zero-padded
//      to a multiple of 8 (pad pairs contribute w=0 * v[0] = exactly 0).
//   5. out = P@v sparse gather, column-sliced (slice = 128 cols = 2 MB,
//      L2-resident per XCD via linear%8 dispatch; FETCH 788->28 MB).
// Round 19 = round 18 with the softmax stripe-stride bug fixed: a wave
// covers 64 lanes x 8 elems = 512 ushorts per stripe (NOT 1024; round 18
// read past its row and emitted idx>8191 -> absmax 52). Wave-autonomous
// softmax: one wave per row, row register-resident (16 x ushortx8),
// 4-way partial max/sum chains + shfl_xor reductions, ballot-prefix
// compaction (no barriers, no LDS, no atomics). Numerics identical to
// round 17 (exact row max, f32 exp, single f2h rounding).

typedef _Float16 f16x8 __attribute__((ext_vector_type(8)));
typedef float floatx4 __attribute__((ext_vector_type(4)));
typedef float floatx2 __attribute__((ext_vector_type(2)));
typedef unsigned short ushortx8 __attribute__((ext_vector_type(8)));

__device__ __forceinline__ unsigned short f2h(float f) {
  __half h = __float2half(f);
  return __builtin_bit_cast(unsigned short, h);
}
__device__ __forceinline__ float h2f(unsigned short u) {
  return __half2float(__builtin_bit_cast(__half, u));
}

// async global->LDS, 16B per lane. LDS dest is wave-uniform base; HW adds lane*16.
__device__ __forceinline__ void async16(const void* g, void* l) {
  __builtin_amdgcn_global_load_lds(
      (__attribute__((address_space(1))) unsigned int*)(g),
      (__attribute__((address_space(3))) unsigned int*)(l),
      16, 0, 0);
}

// ---------------- conversions / transposes ----------------

__global__ __launch_bounds__(256) void conv_f32_f16(const float* __restrict__ in,
                                                    unsigned short* __restrict__ out,
                                                    long n) {
  long i = ((long)blockIdx.x * 256 + threadIdx.x) * 4;
  if (i + 3 < n) {
    float4 f = *(const float4*)(in + i);
    ushort4 o;
    o.x = f2h(f.x); o.y = f2h(f.y); o.z = f2h(f.z); o.w = f2h(f.w);
    *(ushort4*)(out + i) = o;
  }
}

// in[rows][cols] fp32 -> out[cols][rows] fp16; z selects one of 3 matrices
__global__ __launch_bounds__(256) void transpose_f32_f16_3(const float* __restrict__ in0,
                                                           const float* __restrict__ in1,
                                                           const float* __restrict__ in2,
                                                           unsigned short* __restrict__ out,
                                                           int rows, int cols) {
  const float* in = (blockIdx.z == 0) ? in0 : (blockIdx.z == 1) ? in1 : in2;
  unsigned short* o = out + (size_t)blockIdx.z * rows * cols;
  __shared__ float tile[32][33];
  int bx = blockIdx.x * 32;
  int by = blockIdx.y * 32;
  int tx = threadIdx.x & 31, ty = threadIdx.x >> 5;
  #pragma unroll
  for (int yy = ty; yy < 32; yy += 8)
    tile[yy][tx] = in[(size_t)(by + yy) * cols + bx + tx];
  __syncthreads();
  #pragma unroll
  for (int yy = ty; yy < 32; yy += 8)
    o[(size_t)(bx + yy) * rows + by + tx] = f2h(tile[tx][yy]);
}

// ---- GEMM 128x128 (m97 recipe): C[M][Nn] = A[M][K]*B[Nn][K]^T, fp16 in, f32 acc ----
// MODE 0: batched proj (blockIdx.z selects W/bias/out; +bias[col], fp16 store)
// MODE 1: plain fp16 store (scores)
// Epilogue: acc -> LDS fp16 tile (aliased over As/Bs; row stride padded to
// 136 ushorts) -> full-line global stores (whole 64B lines, no
// write-allocate fetch).
template <int MODE>
__global__ __launch_bounds__(256, 4)
void gemm_bt(const unsigned short* __restrict__ A,
             const unsigned short* __restrict__ B,
             int M, int Nn, int K,
             const float* __restrict__ b0, const float* __restrict__ b1,
             const float* __restrict__ b2,
             unsigned short* __restrict__ out) {
  if constexpr (MODE == 0) {
    B   += (size_t)blockIdx.z * Nn * K;
    out += (size_t)blockIdx.z * M * Nn;
  }
  const float* bias = (MODE != 0) ? nullptr
                      : (blockIdx.z == 0) ? b0 : (blockIdx.z == 1) ? b1 : b2;
  // smem layout: [As 4096][Bs 4096] during K-loop; whole buffer reused as
  // the 128x136 (padded) fp16 C tile in the epilogue (after final barrier).
  __shared__ unsigned short smem[128 * 136];
  unsigned short* As = smem;
  unsigned short* Bs = smem + 128 * 32;
  const int tid  = threadIdx.x;
  const int wave = tid >> 6;
  const int lane = tid & 63;
  const int wm = wave >> 1, wn = wave & 1;
  const int quad = lane >> 4, l16 = lane & 15;
  const long bm = (long)blockIdx.y * 128;
  const long bn = (long)blockIdx.x * 128;

  floatx4 acc[4][4] = {};

  const int srow = wave * 32 + (lane >> 2);
  const int scol = (lane & 3) * 8;
  const unsigned short* gA0 = A + (bm + srow) * (long)K + scol;
  const unsigned short* gA1 = gA0 + 16L * K;
  const unsigned short* gB0 = B + (bn + srow) * (long)K + scol;
  const unsigned short* gB1 = gB0 + 16L * K;
  unsigned short* lA0 = &As[(wave * 32) * 32];
  unsigned short* lA1 = &As[(wave * 32 + 16) * 32];
  unsigned short* lB0 = &Bs[(wave * 32) * 32];
  unsigned short* lB1 = &Bs[(wave * 32 + 16) * 32];

  for (int kk = 0; kk < K; kk += 32) {
    async16(gA0 + kk, lA0);
    async16(gA1 + kk, lA1);
    async16(gB0 + kk, lB0);
    async16(gB1 + kk, lB1);
    __syncthreads();
    f16x8 af[4], bfv[4];
    #pragma unroll
    for (int i = 0; i < 4; ++i) {
      af[i]  = *reinterpret_cast<const f16x8*>(&As[(wm * 64 + i * 16 + l16) * 32 + quad * 8]);
      bfv[i] = *reinterpret_cast<const f16x8*>(&Bs[(wn * 64 + i * 16 + l16) * 32 + quad * 8]);
    }
    #pragma unroll
    for (int i = 0; i < 4; ++i)
      #pragma unroll
      for (int j = 0; j < 4; ++j)
        acc[i][j] = __builtin_amdgcn_mfma_f32_16x16x32_f16(af[i], bfv[j], acc[i][j], 0, 0, 0);
    __syncthreads();
  }
  // all waves past the final barrier: As/Bs dead, reuse smem as C tile
  #pragma unroll
  for (int i = 0; i < 4; ++i) {
    const int row0 = wm * 64 + i * 16 + quad * 4;
    #pragma unroll
    for (int j = 0; j < 4; ++j) {
      const int col = wn * 64 + j * 16 + l16;
      const float cb = (MODE == 0) ? bias[bn + col] : 0.0f;
      #pragma unroll
      for (int r = 0; r < 4; ++r)
        smem[(row0 + r) * 136 + col] = f2h(acc[i][j][r] + cb);
    }
  }
  __syncthreads();
  // coalesced store: chunk = 16B; 2048 chunks; wave-instr = 4 rows x 256B
  #pragma unroll
  for (int u = 0; u < 8; ++u) {
    const int chunk = u * 256 + tid;
    const int row = chunk >> 4;
    const int cc = chunk & 15;
    const ushortx8 val = *reinterpret_cast<const ushortx8*>(&smem[row * 136 + cc * 8]);
    *reinterpret_cast<ushortx8*>(&out[(bm + row) * (long)Nn + bn + cc * 8]) = val;
  }
}

// ---- softmax + compaction: ONE WAVE PER ROW ----
// Stripe = 64 lanes x 8 elems = 512 ushorts (1KB); 16 stripes cover the
// 8192-elem row. elem idx = u*512 + lane*8 + e. Exact row max, f32 exp,
// single f2h rounding (reference-identical numerics). Nonzeros packed as
// (idx<<16|halfbits) u32 pairs via ballot prefix-sum (no LDS/atomics),
// zero-padded to a multiple of 8. nnz[row] = padded count.
__global__ __launch_bounds__(256) void softmax_compact(unsigned short* __restrict__ S,
                                                       int* __restrict__ nnz, int n) {
  const int wid  = threadIdx.x >> 6;
  const int lane = threadIdx.x & 63;
  const int row  = blockIdx.x * 4 + wid;
  unsigned short* prow = S + ((size_t)row << 13);  // n = 8192

  // load: 16 x 16B per lane, 1 KB per wave-instr, fully coalesced
  ushortx8 c[16];
  #pragma unroll
  for (int u = 0; u < 16; ++u)
    c[u] = *reinterpret_cast<const ushortx8*>(&prow[u * 512 + lane * 8]);

  // pass 1: row max (4 partial chains -> exact max)
  float m0 = -1e30f, m1 = -1e30f, m2 = -1e30f, m3 = -1e30f;
  #pragma unroll
  for (int u = 0; u < 16; ++u) {
    m0 = fmaxf(m0, fmaxf(h2f(c[u][0]), h2f(c[u][4])));
    m1 = fmaxf(m1, fmaxf(h2f(c[u][1]), h2f(c[u][5])));
    m2 = fmaxf(m2, fmaxf(h2f(c[u][2]), h2f(c[u][6])));
    m3 = fmaxf(m3, fmaxf(h2f(c[u][3]), h2f(c[u][7])));
  }
  float m = fmaxf(fmaxf(m0, m1), fmaxf(m2, m3));
  #pragma unroll
  for (int off = 32; off > 0; off >>= 1)
    m = fmaxf(m, __shfl_xor(m, off, 64));

  // pass 2: denom = sum(exp(v - m)) (4 partial chains)
  float s0 = 0.f, s1 = 0.f, s2 = 0.f, s3 = 0.f;
  #pragma unroll
  for (int u = 0; u < 16; ++u) {
    s0 += __expf(h2f(c[u][0]) - m) + __expf(h2f(c[u][4]) - m);
    s1 += __expf(h2f(c[u][1]) - m) + __expf(h2f(c[u][5]) - m);
    s2 += __expf(h2f(c[u][2]) - m) + __expf(h2f(c[u][6]) - m);
    s3 += __expf(h2f(c[u][3]) - m) + __expf(h2f(c[u][7]) - m);
  }
  float s = (s0 + s1) + (s2 + s3);
  #pragma unroll
  for (int off = 32; off > 0; off >>= 1)
    s += __shfl_xor(s, off, 64);
  const float inv = 1.0f / s;

  // pass 3: recompute exp, scale, round to fp16; ballot-prefix compaction
  unsigned int* pairs = (unsigned int*)prow;
  const int cap = 4096 - 8;
  int base = 0;
  #pragma unroll
  for (int u = 0; u < 16; ++u) {
    #pragma unroll
    for (int e = 0; e < 8; ++e) {
      const unsigned short hh = f2h(__expf(h2f(c[u][e]) - m) * inv);
      const unsigned long long mask = __ballot(hh != 0);
      if (hh) {
        const int pos = base + (int)__popcll(mask & ((1ull << lane) - 1ull));
        if (pos < cap)
          pairs[pos] = ((unsigned)(u * 512 + lane * 8 + e) << 16) | hh;
      }
      base += (int)__popcll(mask);
    }
  }
  const int c_cl = base < cap ? base : cap;
  const int padded = (c_cl + 7) & ~7;
  if (lane < padded - c_cl) pairs[c_cl + lane] = 0u;  // zero pair: exact no-op
  if (lane == 0) nnz[row] = padded;
}

// ---- sparse PV, column-sliced: out[row][slice cols] = sum_j P_j * v[idx_j][cols] ----
// grid = (8 slices, N/16 row-groups) = 4096 blocks = 16/CU. Slice s =
// cols [128s,128s+128) of v = 2 MB, L2-resident on XCD s (linear%8 dispatch).
// Each wave: 4 STRIDED rows (row = by + (wave*4+r)*512), lane owns 2 cols.
// Next pair-quad prefetched branchlessly during the current 8 gathers; all
// loads via uniform base + 32-bit byte voffset; cnt scalar via readfirstlane,
// clamped to [0,4096]. (unchanged; 183-185us plateau)
__global__ __launch_bounds__(256) void pv_sliced(const unsigned short* __restrict__ S,
                                                 const int* __restrict__ nnz,
                                                 const unsigned short* __restrict__ v,
                                                 float* __restrict__ out,
                                                 int n) {
  const int wave = threadIdx.x >> 6;
  const int lane = threadIdx.x & 63;
  const int colbase = blockIdx.x * 128 + lane * 2;
  const unsigned colbyte = (unsigned)colbase * 2;
  const char* __restrict__ vb = (const char*)v;
  const char* __restrict__ sb = (const char*)S;

  #pragma unroll 1
  for (int r = 0; r < 4; ++r) {
    const int row = blockIdx.y + ((wave << 2) + r) * 512;  // strided row map
    int craw = nnz[row];
    craw = craw < 0 ? 0 : (craw > 4096 ? 4096 : craw);
    const int cnt = __builtin_amdgcn_readfirstlane(craw);  // wave-uniform
    const unsigned rowbase = (unsigned)row << 14;          // 16 KB pair slot
    const unsigned pend = rowbase + 16384 - 32;
    unsigned poff = rowbase;
    uint4 q0 = *(const uint4*)(sb + poff);
    uint4 q1 = *(const uint4*)(sb + poff + 16);
    float a0 = 0.f, a1 = 0.f;
    for (int j = 0; j < cnt; j += 8) {
      const unsigned pn = (poff + 32 <= pend) ? poff + 32 : pend;  // branchless clamp
      const uint4 n0 = *(const uint4*)(sb + pn);       // prefetch next quad
      const uint4 n1 = *(const uint4*)(sb + pn + 16);
      const unsigned p[8] = {q0.x, q0.y, q0.z, q0.w, q1.x, q1.y, q1.z, q1.w};
      #pragma unroll
      for (int u = 0; u < 8; ++u) {
        const ushort2 vv = *(const ushort2*)(vb + (((p[u] & 0xffff0000u) >> 5) + colbyte));
        const float w = h2f((unsigned short)(p[u] & 0xffffu));
        a0 += w * h2f(vv.x);
        a1 += w * h2f(vv.y);
      }
      q0 = n0; q1 = n1; poff = pn;
    }
    floatx2 o = {a0, a1};
    __builtin_nontemporal_store(o, (floatx2*)(out + ((size_t)row << 10) + colbase));
  }
}

// ---------------- launch ----------------
extern "C" void kernel_launch(void* const* d_in, const int* in_sizes, int n_in,
                              void* d_out, int out_size, void* d_ws, size_t ws_size,
                              hipStream_t stream) {
  const int N = 8192, H = 1024;
  const float* x  = (const float*)d_in[0];
  const float* Wq = (const float*)d_in[1];
  const float* bq = (const float*)d_in[2];
  const float* Wk = (const float*)d_in[3];
  const float* bk = (const float*)d_in[4];
  const float* Wv = (const float*)d_in[5];
  const float* bv = (const float*)d_in[6];

  char* p = (char*)d_ws;
  unsigned short* xh  = (unsigned short*)p; p += (size_t)N * H * 2;      // 16 MB
  unsigned short* WT  = (unsigned short*)p; p += (size_t)3 * H * H * 2;  // 6 MB
  unsigned short* qkv = (unsigned short*)p; p += (size_t)3 * N * H * 2;  // 48 MB
  unsigned short* S   = (unsigned short*)p; p += (size_t)N * N * 2;      // 128 MB
  int*            nnz = (int*)p;            p += (size_t)N * 4;          // 32 KB
  if ((size_t)(p - (char*)d_ws) > ws_size) return;
  unsigned short* qh = qkv;
  unsigned short* kh = qkv + (size_t)N * H;
  unsigned short* vh = qkv + (size_t)2 * N * H;

  conv_f32_f16<<<(N * H / 4 + 255) / 256, 256, 0, stream>>>(x, xh, (long)N * H);
  transpose_f32_f16_3<<<dim3(H / 32, H / 32, 3), 256, 0, stream>>>(Wq, Wk, Wv, WT, H, H);

  // batched projections: qkv[z][N][H] fp16
  gemm_bt<0><<<dim3(H / 128, N / 128, 3), 256, 0, stream>>>(xh, WT, N, H, H,
                                                            bq, bk, bv, qkv);

  // scores: S[N][N] fp16
  gemm_bt<1><<<dim3(N / 128, N / 128), 256, 0, stream>>>(qh, kh, N, N, H,
                                                         nullptr, nullptr, nullptr, S);
  // softmax + in-place compaction: one wave per row, 2048 blocks
  softmax_compact<<<N / 4, 256, 0, stream>>>(S, nnz, N);
  // sparse PV gather, column-sliced for per-XCD L2 residency (16 blocks/CU)
  pv_sliced<<<dim3(8, N / 16), 256, 0, stream>>>(S, nnz, vh, (float*)d_out, N);
}